// Round 1
// 256.566 us; speedup vs baseline: 1.0779x; 1.0779x over previous
//
#include <hip/hip_runtime.h>

// Tensor Fusion Network, MI355X. Round 3.
// k1: fusion[b][p] bf16 (p = ij*97+k) via per-wave MFMA, barrier-free main loop.
//     (+ zeroes the 31-elem pad so k2's direct A-loads never see poison)
// k2: split-K GEMM, REWRITTEN: 512 thr / 8 waves, A-frags loaded directly from
//     global (fusion[b][p] layout == MFMA A-frag layout, 64B/row/step sectors),
//     W1 staged via double-buffered LDS, ONE barrier per 32-K step, next-step
//     loads issued before current-step MFMAs.
// k3: parallel reduce + bias + relu, 512 thr (2 waves/SIMD).
// k4: fused h2 = relu(h1@W2+b2) and out = sigmoid(h2@W3+b3)*6-3.

#define B_    128
#define T_    64
#define A1    49
#define V1    49
#define X1    97
#define IJ    2401      // 49*49
#define KTOT  232897    // IJ*97
#define FP    232928    // KTOT padded to multiple of 32
#define PF    128
#define KC    512
#define NB2   455       // ceil(FP/KC)

typedef short s8v __attribute__((ext_vector_type(8)));   // 8 bf16
typedef float f4v __attribute__((ext_vector_type(4)));   // 4 fp32

__device__ __forceinline__ unsigned short f2bf(float f) {
    union { float f; unsigned u; } v; v.f = f;
    return (unsigned short)((v.u + 0x7FFFu + ((v.u >> 16) & 1u)) >> 16); // RNE
}

// ---------------- k1: fusion (bf16) -------------------------------------
// grid (4, 128): blockIdx.y = b, blockIdx.x covers 38 ij-tiles of 16 (151 total).
// 512 threads = 8 waves; each wave owns a private w-slice in LDS -> no barriers
// after initial staging.
__global__ __launch_bounds__(512) void k1_fusion(
    const float* __restrict__ audio, const float* __restrict__ video,
    const float* __restrict__ text, unsigned short* __restrict__ fusion)
{
    __shared__ float a_s[T_ * A1];                 // [t][i]
    __shared__ float v_s[T_ * V1];                 // [t][j]
    __shared__ unsigned short xT[112 * 72];        // [k][t], rows padded to 72
    __shared__ unsigned short w_ws[8][16 * 72];    // per-wave [ij_local][t]

    const int b = blockIdx.y;
    const int bx = blockIdx.x;
    const int tid = threadIdx.x;

    for (int idx = tid; idx < T_ * A1; idx += 512) {
        int t = idx / 49, i = idx - t * 49;
        a_s[idx] = (i == 0) ? 1.0f : audio[(b * T_ + t) * 48 + (i - 1)];
        v_s[idx] = (i == 0) ? 1.0f : video[(b * T_ + t) * 48 + (i - 1)];
    }
    for (int idx = tid; idx < T_ * X1; idx += 512) {
        int t = idx / 97, k = idx - t * 97;
        xT[k * 72 + t] = f2bf((k == 0) ? 1.0f : text[(b * T_ + t) * 96 + (k - 1)]);
    }
    for (int idx = tid; idx < 15 * 64; idx += 512) {   // zero pad rows k=97..111
        xT[(97 + (idx >> 6)) * 72 + (idx & 63)] = 0;
    }
    if (bx == 0) {                                      // zero fusion pad [KTOT,FP)
        for (int idx = tid; idx < FP - KTOT; idx += 512)
            fusion[(size_t)b * FP + KTOT + idx] = 0;
    }
    __syncthreads();

    const int wave = tid >> 6, lane = tid & 63;
    const int q = lane >> 4, ln = lane & 15;
    unsigned short* w_s = w_ws[wave];

    for (int it = 0; it < 5; ++it) {
        const int tw = it * 8 + wave;          // tile-within-x-block
        if (tw >= 38) break;                   // wave-uniform
        const int tl = bx * 38 + tw;           // global 16-ij tile
        if (tl >= 151) break;
        const int ij0 = tl * 16;

        // w-compute: lane = t, loop over 16 local ij (ij wave-uniform per iter)
        #pragma unroll
        for (int ijl = 0; ijl < 16; ++ijl) {
            int ij = ij0 + ijl;
            unsigned short wv = 0;
            if (ij < IJ) {
                int i = ij / 49, j = ij - i * 49;
                wv = f2bf(a_s[lane * 49 + i] * v_s[lane * 49 + j]);
            }
            w_s[ijl * 72 + lane] = wv;
        }
        // A-frags: lane holds A[m=ln][t = q*8 + 0..7 (+32)]
        s8v af0 = *(const s8v*)&w_s[ln * 72 + q * 8];
        s8v af1 = *(const s8v*)&w_s[ln * 72 + 32 + q * 8];
        #pragma unroll
        for (int nt = 0; nt < 7; ++nt) {
            s8v bf0 = *(const s8v*)&xT[(nt * 16 + ln) * 72 + q * 8];
            s8v bf1 = *(const s8v*)&xT[(nt * 16 + ln) * 72 + 32 + q * 8];
            f4v acc = {0.f, 0.f, 0.f, 0.f};
            acc = __builtin_amdgcn_mfma_f32_16x16x32_bf16(af0, bf0, acc, 0, 0, 0);
            acc = __builtin_amdgcn_mfma_f32_16x16x32_bf16(af1, bf1, acc, 0, 0, 0);
            int kk = nt * 16 + ln;             // C: col=ln -> k, row=q*4+r -> ij
            if (kk < X1) {
                #pragma unroll
                for (int r = 0; r < 4; ++r) {
                    int ij = ij0 + q * 4 + r;
                    if (ij < IJ)
                        fusion[(size_t)b * FP + ij * X1 + kk] = f2bf(acc[r]);
                }
            }
        }
    }
}

// ---------------- k2: split-K GEMM h1-partials --------------------------
// 512 threads = 8 waves; wave w owns b-rows [16w, 16w+16). A-frags come
// straight from global (fusion row-major == frag layout; 64B/row/step).
// W1 (B operand) staged bf16-transposed in double-buffered LDS; one barrier
// per 32-K step; next step's global loads issued before current MFMAs.
#define BPAD 40   // LDS row pad (elements): 80B rows keep b128 reads 16B-aligned
__global__ __launch_bounds__(512) void k2_gemm(
    const unsigned short* __restrict__ fusion, const float* __restrict__ W1,
    float* __restrict__ partials)
{
    __shared__ unsigned short B_l[2][128 * BPAD];  // [f][p_local], 2 buffers

    const int blk = blockIdx.x;
    const int kbase = blk * KC;
    const int nsteps = min(KC >> 5, (FP - kbase) >> 5);
    const int tid = threadIdx.x;
    const int wave = tid >> 6, lane = tid & 63;
    const int q = lane >> 4, ln = lane & 15;

    const int fB = tid & 127, g = tid >> 7;    // B-stage: thread -> (f, 8-p group)

    const unsigned short* Arow =
        fusion + (size_t)(wave * 16 + ln) * FP + kbase + q * 8;

    f4v acc[8];
    #pragma unroll
    for (int n = 0; n < 8; ++n) acc[n] = (f4v){0.f, 0.f, 0.f, 0.f};

    // prologue: stage step 0 into buffer 0
    {
        float bv[8];
        #pragma unroll
        for (int c = 0; c < 8; ++c) {
            int p = kbase + g * 8 + c;
            bv[c] = (p < KTOT) ? W1[(size_t)p * PF + fB] : 0.f;
        }
        ushort4 lo, hi;
        lo.x = f2bf(bv[0]); lo.y = f2bf(bv[1]); lo.z = f2bf(bv[2]); lo.w = f2bf(bv[3]);
        hi.x = f2bf(bv[4]); hi.y = f2bf(bv[5]); hi.z = f2bf(bv[6]); hi.w = f2bf(bv[7]);
        *(ushort4*)&B_l[0][fB * BPAD + g * 8]     = lo;
        *(ushort4*)&B_l[0][fB * BPAD + g * 8 + 4] = hi;
    }
    s8v av = *(const s8v*)Arow;
    __syncthreads();

    for (int s = 0; s < nsteps; ++s) {
        const int cbuf = s & 1, nbuf = cbuf ^ 1;
        float bvn[8];
        s8v avn;
        const bool more = (s + 1 < nsteps);    // wave-uniform
        if (more) {                            // issue next-step globals early
            const int p1 = kbase + (s + 1) * 32;
            #pragma unroll
            for (int c = 0; c < 8; ++c) {
                int p = p1 + g * 8 + c;
                bvn[c] = (p < KTOT) ? W1[(size_t)p * PF + fB] : 0.f;
            }
            avn = *(const s8v*)(Arow + (s + 1) * 32);
        }
        #pragma unroll
        for (int nt = 0; nt < 8; ++nt) {
            s8v bf = *(const s8v*)&B_l[cbuf][(nt * 16 + ln) * BPAD + q * 8];
            acc[nt] = __builtin_amdgcn_mfma_f32_16x16x32_bf16(av, bf, acc[nt], 0, 0, 0);
        }
        if (more) {
            ushort4 lo, hi;
            lo.x = f2bf(bvn[0]); lo.y = f2bf(bvn[1]); lo.z = f2bf(bvn[2]); lo.w = f2bf(bvn[3]);
            hi.x = f2bf(bvn[4]); hi.y = f2bf(bvn[5]); hi.z = f2bf(bvn[6]); hi.w = f2bf(bvn[7]);
            *(ushort4*)&B_l[nbuf][fB * BPAD + g * 8]     = lo;
            *(ushort4*)&B_l[nbuf][fB * BPAD + g * 8 + 4] = hi;
            av = avn;
        }
        __syncthreads();   // next buffer ready; also fences this buffer's reads
    }

    float* outp = partials + (size_t)blk * (128 * 128);
    #pragma unroll
    for (int nt = 0; nt < 8; ++nt) {
        const int f = nt * 16 + ln;
        #pragma unroll
        for (int r = 0; r < 4; ++r)
            outp[(wave * 16 + q * 4 + r) * 128 + f] = acc[nt][r];
    }
}

// ---------------- k3: reduce partials + bias + relu ---------------------
// grid 256 blocks x 512 thr: block owns 64 e-values, 8-way r-split per e.
__global__ __launch_bounds__(512) void k3_reduce(
    const float* __restrict__ partials, const float* __restrict__ b1,
    float* __restrict__ h1)
{
    __shared__ float red[512];
    const int e = blockIdx.x * 64 + (threadIdx.x & 63);
    const int rh = threadIdx.x >> 6;           // 0..7
    float s = 0.f;
    for (int r = rh; r < NB2; r += 8)
        s += partials[(size_t)r * 16384 + e];
    red[threadIdx.x] = s;
    __syncthreads();
    if (threadIdx.x < 64) {
        float v = 0.f;
        #pragma unroll
        for (int j = 0; j < 8; ++j) v += red[threadIdx.x + 64 * j];
        v += b1[e & 127];
        h1[e] = fmaxf(v, 0.f);
    }
}

// ---------------- k4: h2 = relu(h1@W2+b2); out = sigmoid(h2@W3+b3)*6-3 --
__global__ __launch_bounds__(128) void k4_out(
    const float* __restrict__ h1, const float* __restrict__ W2,
    const float* __restrict__ b2, const float* __restrict__ W3,
    const float* __restrict__ b3, float* __restrict__ out)
{
    __shared__ float hrow[128];
    __shared__ float red2[2];
    const int b = blockIdx.x, f = threadIdx.x;
    hrow[f] = h1[b * 128 + f];
    __syncthreads();
    float s = b2[f];
    #pragma unroll 8
    for (int c = 0; c < 128; ++c) s += hrow[c] * W2[c * 128 + f];
    float p = fmaxf(s, 0.f) * W3[f];
    #pragma unroll
    for (int off = 32; off; off >>= 1) p += __shfl_down(p, off, 64);
    if ((f & 63) == 0) red2[f >> 6] = p;
    __syncthreads();
    if (f == 0) {
        float t = red2[0] + red2[1] + b3[0];
        out[b] = 6.0f / (1.0f + expf(-t)) - 3.0f;
    }
}

extern "C" void kernel_launch(void* const* d_in, const int* in_sizes, int n_in,
                              void* d_out, int out_size, void* d_ws, size_t ws_size,
                              hipStream_t stream)
{
    const float* audio = (const float*)d_in[0];
    const float* video = (const float*)d_in[1];
    const float* text  = (const float*)d_in[2];
    const float* W1 = (const float*)d_in[3];
    const float* b1 = (const float*)d_in[4];
    const float* W2 = (const float*)d_in[5];
    const float* b2 = (const float*)d_in[6];
    const float* W3 = (const float*)d_in[7];
    const float* b3 = (const float*)d_in[8];
    float* out = (float*)d_out;

    // ws layout: fusion bf16 [128][FP] = 59,629,568 B
    //            partials fp32 [455][16384] = 29,818,880 B @ 59,629,568
    //            h1 @ 89,448,448 ; total 89,513,984 B
    char* ws = (char*)d_ws;
    unsigned short* fusion = (unsigned short*)ws;
    float* partials = (float*)(ws + 59629568);
    float* h1 = (float*)(ws + 89448448);

    k1_fusion<<<dim3(4, 128), 512, 0, stream>>>(audio, video, text, fusion);
    k2_gemm<<<dim3(NB2), 512, 0, stream>>>(fusion, W1, partials);
    k3_reduce<<<dim3(256), 512, 0, stream>>>(partials, b1, h1);
    k4_out<<<dim3(128), 128, 0, stream>>>(h1, W2, b2, W3, b3, out);
}